// Round 18
// baseline (350.636 us; speedup 1.0000x reference)
//
#include <hip/hip_runtime.h>
#include <hip/hip_bf16.h>

#define NN 50000
#define EE 800000
#define IN_DIM 128
#define HH 128
#define HEADS 4
#define CC 32
#define LL 3
#define NCLS 10
#define NGRAPH 64
#define SNB ((NN + 1023) / 1024)  // 49 scan blocks

using short8 = __attribute__((ext_vector_type(8))) short;
using f32x4 = __attribute__((ext_vector_type(4))) float;

__device__ inline float lrelu(float x) { return fmaxf(x, 0.2f * x); }
__device__ inline float fexp(float x) { return __expf(x); }

__device__ inline float bf2f(ushort u) {
    union { uint32_t i; float f; } c;
    c.i = ((uint32_t)u) << 16;
    return c.f;
}
__device__ inline ushort f2bf(float f) {
    union { float f; uint32_t i; } c;
    c.f = f;
    uint32_t x = c.i;
    uint32_t r = (x + 0x7fffu + ((x >> 16) & 1u)) >> 16;
    return (ushort)r;
}

__device__ inline float wred_sum(float v) {
#pragma unroll
    for (int m = 32; m >= 1; m >>= 1) v += __shfl_xor(v, m, 64);
    return v;
}

__device__ inline float pick4(int h, float a, float b, float c, float d) {
    float ab = (h & 1) ? b : a;
    float cd = (h & 1) ? d : c;
    return (h & 2) ? cd : ab;
}

// ---------------- weights -> W^T bf16, pre-swizzled (16B unit u ^= n&7)
__global__ __launch_bounds__(256) void prep_weights(const float* __restrict__ W_node,
                                                    const float* __restrict__ W_gat,
                                                    ushort* __restrict__ WT) {
    int b = blockIdx.x;
    const float* W = (b == 0) ? W_node : (W_gat + (size_t)(b - 1) * 16384);
    ushort* D = WT + (size_t)b * 16384;
    int t = threadIdx.x;
    int n = t >> 1;
    int k0 = (t & 1) * 64;
    for (int kk = 0; kk < 64; kk++) {
        int k = k0 + kk;
        float v = W[k * 128 + n];
        int u = (k >> 3) ^ (n & 7);
        D[n * 128 + u * 8 + (k & 7)] = f2bf(v);
    }
}

// ---------------- MFMA GEMM: out_bf[N,128] = A[N,128] @ W  (W^T staged in LDS)
// BM=256: 4 row-groups of 16 per wave reuse one W-stage (staging amortized 4x).
// AF32 1: A is fp32 (node-init). MODE 1: +b_node+temb. SCORES 1: emit s_src/s_dst.
template <int MODE, int SCORES, int AF32>
__global__ __launch_bounds__(256) void gemm_mfma(
    const ushort* __restrict__ Abf, const float* __restrict__ Af32,
    const ushort* __restrict__ WT, ushort* __restrict__ out_bf,
    const float* __restrict__ bias, const int* __restrict__ ntypes,
    const float* __restrict__ temb,
    const float* __restrict__ asrc, const float* __restrict__ adst,
    float* __restrict__ s_src, float* __restrict__ s_dst, int nrows) {
    __shared__ ushort wlds[16384];
    int tid = threadIdx.x;
    int lane = tid & 63;
    int wid = tid >> 6;

    {
        const short8* src = (const short8*)WT;
        short8* dst = (short8*)wlds;
#pragma unroll
        for (int i = 0; i < 8; i++) dst[i * 256 + tid] = src[i * 256 + tid];
    }

    int cgrp = lane & 15;
    int kgrp = lane >> 4;
    int rbase0 = blockIdx.x * 256 + wid * 64;

    float as[8], ad[8];
    if (SCORES) {
#pragma unroll
        for (int nt = 0; nt < 8; nt++) {
            as[nt] = asrc[nt * 16 + cgrp];
            ad[nt] = adst[nt * 16 + cgrp];
        }
    }

    __syncthreads();

    for (int rg = 0; rg < 4; rg++) {
        int rbase = rbase0 + rg * 16;
        if (rbase >= nrows) break;
        int arow = rbase + (lane & 15);
        if (arow >= nrows) arow = nrows - 1;

        short8 afr[4];
        if (AF32) {
            const float4* ap = (const float4*)(Af32 + (size_t)arow * 128);
#pragma unroll
            for (int ks = 0; ks < 4; ks++) {
                float4 f0 = ap[ks * 8 + kgrp * 2];
                float4 f1 = ap[ks * 8 + kgrp * 2 + 1];
                short8 a;
                a[0] = (short)f2bf(f0.x); a[1] = (short)f2bf(f0.y);
                a[2] = (short)f2bf(f0.z); a[3] = (short)f2bf(f0.w);
                a[4] = (short)f2bf(f1.x); a[5] = (short)f2bf(f1.y);
                a[6] = (short)f2bf(f1.z); a[7] = (short)f2bf(f1.w);
                afr[ks] = a;
            }
        } else {
            const short8* ap = (const short8*)(Abf + (size_t)arow * 128);
#pragma unroll
            for (int ks = 0; ks < 4; ks++) afr[ks] = ap[ks * 4 + kgrp];
        }

        f32x4 acc[8];
#pragma unroll
        for (int i = 0; i < 8; i++) acc[i] = (f32x4){0.f, 0.f, 0.f, 0.f};

#pragma unroll
        for (int ks = 0; ks < 4; ks++) {
            short8 a = afr[ks];
#pragma unroll
            for (int nt = 0; nt < 8; nt++) {
                int n = nt * 16 + cgrp;
                int u = (ks * 4 + kgrp) ^ (n & 7);
                short8 b = *(const short8*)&wlds[n * 128 + u * 8];
                acc[nt] = __builtin_amdgcn_mfma_f32_16x16x32_bf16(a, b, acc[nt], 0, 0, 0);
            }
        }

        int nts[4];
        if (MODE == 1) {
#pragma unroll
            for (int r = 0; r < 4; r++) {
                int row = rbase + kgrp * 4 + r;
                nts[r] = (row < nrows) ? ntypes[row] : 0;
            }
        }
#pragma unroll
        for (int nt = 0; nt < 8; nt++) {
            int colc = nt * 16 + cgrp;
#pragma unroll
            for (int r = 0; r < 4; r++) {
                int row = rbase + kgrp * 4 + r;
                if (row < nrows) {
                    float v = acc[nt][r];
                    if (MODE == 1) v += bias[colc] + temb[nts[r] * 128 + colc];
                    out_bf[(size_t)row * 128 + colc] = f2bf(v);
                }
            }
        }

        if (SCORES) {
#pragma unroll
            for (int r = 0; r < 4; r++) {
                float ps[4], pd[4];
#pragma unroll
                for (int hh = 0; hh < 4; hh++) {
                    ps[hh] = acc[2 * hh][r] * as[2 * hh] + acc[2 * hh + 1][r] * as[2 * hh + 1];
                    pd[hh] = acc[2 * hh][r] * ad[2 * hh] + acc[2 * hh + 1][r] * ad[2 * hh + 1];
                }
#pragma unroll
                for (int off = 1; off < 16; off <<= 1) {
#pragma unroll
                    for (int hh = 0; hh < 4; hh++) {
                        ps[hh] += __shfl_xor(ps[hh], off, 64);
                        pd[hh] += __shfl_xor(pd[hh], off, 64);
                    }
                }
                int row = rbase + kgrp * 4 + r;
                if (cgrp == 0 && row < nrows) {
                    ((float4*)s_src)[row] = make_float4(ps[0], ps[1], ps[2], ps[3]);
                    ((float4*)s_dst)[row] = make_float4(pd[0], pd[1], pd[2], pd[3]);
                }
            }
        }
    }
}

// ---------------- CSR build: pass A = count + slot, pass B = non-atomic fill
__global__ void count_slot(const int* __restrict__ dst, int* __restrict__ deg,
                           int* __restrict__ slot, int ne) {
    int i = blockIdx.x * blockDim.x + threadIdx.x;
    if (i < ne) slot[i] = atomicAdd(&deg[dst[i]], 1);
}

__global__ __launch_bounds__(1024) void scan_local(const int* __restrict__ cnt,
                                                   int* __restrict__ rp,
                                                   int* __restrict__ btot, int n) {
    __shared__ int lds[1024];
    int t = threadIdx.x;
    int i = blockIdx.x * 1024 + t;
    int v = (i < n) ? cnt[i] : 0;
    lds[t] = v;
    __syncthreads();
    for (int off = 1; off < 1024; off <<= 1) {
        int u = (t >= off) ? lds[t - off] : 0;
        __syncthreads();
        lds[t] += u;
        __syncthreads();
    }
    if (i < n) rp[i] = lds[t] - v;  // local exclusive
    if (t == 1023) btot[blockIdx.x] = lds[1023];
}

__global__ __launch_bounds__(64) void scan_btot(int* __restrict__ btot) {
    int t = threadIdx.x;
    int v = (t < SNB) ? btot[t] : 0;
#pragma unroll
    for (int off = 1; off < 64; off <<= 1) {
        int u = __shfl_up(v, off, 64);
        if (t >= off) v += u;
    }
    if (t < SNB) btot[t] = v;  // inclusive prefix
}

__global__ __launch_bounds__(1024) void scan_add(int* __restrict__ rp,
                                                 const int* __restrict__ btot, int n) {
    int b = blockIdx.x;
    int i = b * 1024 + threadIdx.x;
    int add = (b == 0) ? 0 : btot[b - 1];
    if (i < n) rp[i] += add;
    if (i == 0) rp[n] = EE;
}

__global__ void fill_pass(const int* __restrict__ ei, const int* __restrict__ row_ptr,
                          const int* __restrict__ slot, int* __restrict__ col, int ne) {
    int i = blockIdx.x * blockDim.x + threadIdx.x;
    if (i < ne) {
        int d = ei[ne + i];
        col[row_ptr[d] + slot[i]] = ei[i];
    }
}

// ---------------- fused GAT aggregate + bias + layernorm + residual relu
__global__ __launch_bounds__(256) void gat_aggregate(
    const ushort* __restrict__ xh, const float* __restrict__ ssrc,
    const float* __restrict__ sdst, const int* __restrict__ row_ptr,
    const int* __restrict__ col, const float* __restrict__ bg,
    const float* __restrict__ lng, const float* __restrict__ lnb,
    ushort* __restrict__ h, int n) {
    int wid = threadIdx.x >> 6;
    int lane = threadIdx.x & 63;
    int node = blockIdx.x * 4 + wid;
    if (node >= n) return;

    int base = row_ptr[node];
    int deg = row_ptr[node + 1] - base;

    float4 sd = ((const float4*)sdst)[node];
    float4 ssf = ((const float4*)ssrc)[node];

    int aj = lane >> 2;
    int ah = lane & 3;
    float sdA = pick4(ah, sd.x, sd.y, sd.z, sd.w);

    int eg = lane >> 4;
    int g = lane & 15;
    int head = g >> 2;
    float sdH = pick4(head, sd.x, sd.y, sd.z, sd.w);
    float esH = lrelu(pick4(head, ssf.x, ssf.y, ssf.z, ssf.w) + sdH);

    float acc[8];
#pragma unroll
    for (int k = 0; k < 8; k++) acc[k] = 0.f;

    float esA = lrelu(pick4(ah, ssf.x, ssf.y, ssf.z, ssf.w) + sdA);
    float zp = (aj == 0) ? fexp(esA) : 0.f;

    if (eg == 0) {  // self-loop message once
        float w = fexp(esH);
        uint4 xv = *(const uint4*)(xh + (size_t)node * 128 + g * 8);
#pragma unroll
        for (int p = 0; p < 4; p++) {
            uint32_t u = (&xv.x)[p];
            acc[2 * p] += w * __uint_as_float(u << 16);
            acc[2 * p + 1] += w * __uint_as_float(u & 0xffff0000u);
        }
    }

    for (int c0 = 0; c0 < deg; c0 += 16) {
        int cn = deg - c0;
        if (cn > 16) cn = 16;
        int ja = aj < cn ? aj : cn - 1;
        int sA = col[base + c0 + ja];
        float sc = ssrc[sA * 4 + ah];
        float w = fexp(lrelu(sc + sdA));
        if (aj >= cn) w = 0.f;
        zp += w;
#pragma unroll
        for (int t = 0; t < 4; t++) {
            int j = t * 4 + eg;
            int s = __shfl(sA, j * 4, 64);
            float wv = __shfl(w, j * 4 + head, 64);
            if (j < cn) {
                uint4 xv = *(const uint4*)(xh + (size_t)s * 128 + g * 8);
#pragma unroll
                for (int p = 0; p < 4; p++) {
                    uint32_t u = (&xv.x)[p];
                    acc[2 * p] += wv * __uint_as_float(u << 16);
                    acc[2 * p + 1] += wv * __uint_as_float(u & 0xffff0000u);
                }
            }
        }
    }

#pragma unroll
    for (int k = 0; k < 8; k++) {
        acc[k] += __shfl_xor(acc[k], 16, 64);
        acc[k] += __shfl_xor(acc[k], 32, 64);
    }
    zp += __shfl_xor(zp, 4, 64);
    zp += __shfl_xor(zp, 8, 64);
    zp += __shfl_xor(zp, 16, 64);
    zp += __shfl_xor(zp, 32, 64);
    float z = __shfl(zp, head, 64);
    float iz = 1.f / (z + 1e-16f);

    const float4* bg4 = (const float4*)(bg + g * 8);
    float4 b0 = bg4[0], b1 = bg4[1];
    float o[8];
    o[0] = acc[0] * iz + b0.x; o[1] = acc[1] * iz + b0.y;
    o[2] = acc[2] * iz + b0.z; o[3] = acc[3] * iz + b0.w;
    o[4] = acc[4] * iz + b1.x; o[5] = acc[5] * iz + b1.y;
    o[6] = acc[6] * iz + b1.z; o[7] = acc[7] * iz + b1.w;

    float ls = 0.f;
#pragma unroll
    for (int k = 0; k < 8; k++) ls += o[k];
    float mu = wred_sum(ls) * (1.f / 512.f);
    float vs = 0.f;
#pragma unroll
    for (int k = 0; k < 8; k++) {
        o[k] -= mu;
        vs += o[k] * o[k];
    }
    float var = wred_sum(vs) * (1.f / 512.f);
    float rs = rsqrtf(var + 1e-5f);

    if (eg == 0) {
        const float4* lg4 = (const float4*)(lng + g * 8);
        const float4* lb4 = (const float4*)(lnb + g * 8);
        float4 g0 = lg4[0], g1 = lg4[1];
        float4 q0 = lb4[0], q1 = lb4[1];
        ushort* hr = h + (size_t)node * 128 + g * 8;
        short8 prev = *(const short8*)hr;
        float y[8];
        y[0] = fmaxf(o[0] * rs * g0.x + q0.x + bf2f((ushort)prev[0]), 0.f);
        y[1] = fmaxf(o[1] * rs * g0.y + q0.y + bf2f((ushort)prev[1]), 0.f);
        y[2] = fmaxf(o[2] * rs * g0.z + q0.z + bf2f((ushort)prev[2]), 0.f);
        y[3] = fmaxf(o[3] * rs * g0.w + q0.w + bf2f((ushort)prev[3]), 0.f);
        y[4] = fmaxf(o[4] * rs * g1.x + q1.x + bf2f((ushort)prev[4]), 0.f);
        y[5] = fmaxf(o[5] * rs * g1.y + q1.y + bf2f((ushort)prev[5]), 0.f);
        y[6] = fmaxf(o[6] * rs * g1.z + q1.z + bf2f((ushort)prev[6]), 0.f);
        y[7] = fmaxf(o[7] * rs * g1.w + q1.w + bf2f((ushort)prev[7]), 0.f);
        short8 ob;
#pragma unroll
        for (int k = 0; k < 8; k++) ob[k] = (short)f2bf(y[k]);
        *(short8*)hr = ob;
    }
}

// ---------------- mean pool (batch sorted -> run-length atomics), bf16 h
__global__ __launch_bounds__(256) void pool_kernel(const ushort* __restrict__ h,
                                                   const int* __restrict__ batch,
                                                   float* __restrict__ sums,
                                                   int* __restrict__ cnts, int n) {
    int c = threadIdx.x & 127;
    int half = threadIdx.x >> 7;
    int n0 = blockIdx.x * 64;
    float acc = 0.f;
    int cur = -1;
    for (int idx = half; idx < 64; idx += 2) {
        int node = n0 + idx;
        if (node >= n) break;
        int g = batch[node];
        if (g != cur) {
            if (cur >= 0) atomicAdd(&sums[cur * 128 + c], acc);
            cur = g;
            acc = 0.f;
        }
        acc += bf2f(h[(size_t)node * 128 + c]);
    }
    if (cur >= 0) atomicAdd(&sums[cur * 128 + c], acc);

    if (c == 0) {
        int cnt = 0, curg = -1;
        for (int idx = half; idx < 64; idx += 2) {
            int node = n0 + idx;
            if (node >= n) break;
            int g = batch[node];
            if (g != curg) {
                if (curg >= 0) atomicAdd(&cnts[curg], cnt);
                curg = g;
                cnt = 0;
            }
            cnt++;
        }
        if (curg >= 0) atomicAdd(&cnts[curg], cnt);
    }
}

// ---------------- MLP head: one block per graph
__global__ __launch_bounds__(256) void head_kernel(
    const float* __restrict__ sums, const int* __restrict__ cnts,
    const float* __restrict__ W1, const float* __restrict__ b1,
    const float* __restrict__ W2, const float* __restrict__ b2,
    const float* __restrict__ W3, const float* __restrict__ b3,
    float* __restrict__ out) {
    __shared__ float hg[128], z1[256], z2[128];
    int g = blockIdx.x;
    int t = threadIdx.x;
    if (t < 128) hg[t] = sums[g * 128 + t] / fmaxf((float)cnts[g], 1.f);
    __syncthreads();
    {
        float acc = b1[t];
        for (int k = 0; k < 128; k++) acc += hg[k] * W1[k * 256 + t];
        z1[t] = fmaxf(acc, 0.f);
    }
    __syncthreads();
    if (t < 128) {
        float acc = b2[t];
        for (int k = 0; k < 256; k++) acc += z1[k] * W2[k * 128 + t];
        z2[t] = fmaxf(acc, 0.f);
    }
    __syncthreads();
    if (t < NCLS) {
        float acc = b3[t];
        for (int k = 0; k < 128; k++) acc += z2[k] * W3[k * NCLS + t];
        out[g * NCLS + t] = acc;
    }
}

extern "C" void kernel_launch(void* const* d_in, const int* in_sizes, int n_in,
                              void* d_out, int out_size, void* d_ws, size_t ws_size,
                              hipStream_t stream) {
    const float* x = (const float*)d_in[0];
    const int* ei = (const int*)d_in[1];
    const int* ntypes = (const int*)d_in[2];
    const int* batch = (const int*)d_in[3];
    const float* W_node = (const float*)d_in[4];
    const float* b_node = (const float*)d_in[5];
    const float* temb = (const float*)d_in[6];
    const float* W_gat = (const float*)d_in[7];
    const float* a_src = (const float*)d_in[8];
    const float* a_dst = (const float*)d_in[9];
    const float* b_gat = (const float*)d_in[10];
    const float* ln_g = (const float*)d_in[11];
    const float* ln_b = (const float*)d_in[12];
    const float* W1 = (const float*)d_in[13];
    const float* b1 = (const float*)d_in[14];
    const float* W2 = (const float*)d_in[15];
    const float* b2 = (const float*)d_in[16];
    const float* W3 = (const float*)d_in[17];
    const float* b3 = (const float*)d_in[18];
    float* out = (float*)d_out;

    char* ws = (char*)d_ws;
    size_t off = 0;
    auto alloc = [&](size_t bytes) {
        void* p = ws + off;
        off += (bytes + 255) & ~(size_t)255;
        return p;
    };
    ushort* hb = (ushort*)alloc((size_t)NN * 128 * 2);   // bf16 h
    ushort* xhb = (ushort*)alloc((size_t)NN * 128 * 2);  // bf16 xh (layer GEMM out)
    ushort* WT = (ushort*)alloc((size_t)4 * 16384 * 2);
    float* ssrc = (float*)alloc((size_t)NN * 4 * 4);
    float* sdst = (float*)alloc((size_t)NN * 4 * 4);
    int* rowp = (int*)alloc((size_t)(NN + 1) * 4);
    int* fillc = (int*)alloc((size_t)NN * 4);
    int* col = (int*)alloc((size_t)EE * 4);
    int* slot = (int*)alloc((size_t)EE * 4);
    float* psum = (float*)alloc((size_t)NGRAPH * 128 * 4);
    int* pcnt = (int*)alloc((size_t)NGRAPH * 4);
    int* btot = (int*)alloc((size_t)SNB * 4);

    hipError_t e0;
    e0 = hipMemsetAsync(fillc, 0, (size_t)NN * 4, stream); (void)e0;
    e0 = hipMemsetAsync(psum, 0, (size_t)NGRAPH * 128 * 4, stream); (void)e0;
    e0 = hipMemsetAsync(pcnt, 0, (size_t)NGRAPH * 4, stream); (void)e0;

    // prep: weights -> W^T bf16 swizzled
    prep_weights<<<4, 256, 0, stream>>>(W_node, W_gat, WT);

    // CSR build: count+slot -> scan -> non-atomic fill
    count_slot<<<(EE + 255) / 256, 256, 0, stream>>>(ei + EE, fillc, slot, EE);
    scan_local<<<SNB, 1024, 0, stream>>>(fillc, rowp, btot, NN);
    scan_btot<<<1, 64, 0, stream>>>(btot);
    scan_add<<<SNB, 1024, 0, stream>>>(rowp, btot, NN);
    fill_pass<<<(EE + 255) / 256, 256, 0, stream>>>(ei, rowp, slot, col, EE);

    // node init: h = x@W_node + b_node + temb[ntypes]  (fp32 A read, bf16 out)
    int gemm_grid = (NN + 255) / 256;
    gemm_mfma<1, 0, 1><<<gemm_grid, 256, 0, stream>>>(
        nullptr, x, WT, hb, b_node, ntypes, temb, nullptr, nullptr, nullptr, nullptr, NN);

    for (int l = 0; l < LL; l++) {
        gemm_mfma<0, 1, 0><<<gemm_grid, 256, 0, stream>>>(
            hb, nullptr, WT + (size_t)(l + 1) * 16384, xhb, nullptr, nullptr, nullptr,
            a_src + l * HEADS * CC, a_dst + l * HEADS * CC, ssrc, sdst, NN);
        gat_aggregate<<<(NN + 3) / 4, 256, 0, stream>>>(
            xhb, ssrc, sdst, rowp, col, b_gat + l * 128, ln_g + l * 128, ln_b + l * 128,
            hb, NN);
    }

    pool_kernel<<<(NN + 63) / 64, 256, 0, stream>>>(hb, batch, psum, pcnt, NN);
    head_kernel<<<NGRAPH, 256, 0, stream>>>(psum, pcnt, W1, b1, W2, b2, W3, b3, out);
}

// Round 19
// 321.567 us; speedup vs baseline: 1.0904x; 1.0904x over previous
//
#include <hip/hip_runtime.h>
#include <hip/hip_bf16.h>

#define NN 50000
#define EE 800000
#define IN_DIM 128
#define HH 128
#define HEADS 4
#define CC 32
#define LL 3
#define NCLS 10
#define NGRAPH 64
#define SNB ((NN + 1023) / 1024)  // 49 scan blocks

using short8 = __attribute__((ext_vector_type(8))) short;
using f32x4 = __attribute__((ext_vector_type(4))) float;

__device__ inline float lrelu(float x) { return fmaxf(x, 0.2f * x); }
__device__ inline float fexp(float x) { return __expf(x); }

__device__ inline float bf2f(ushort u) {
    union { uint32_t i; float f; } c;
    c.i = ((uint32_t)u) << 16;
    return c.f;
}
__device__ inline ushort f2bf(float f) {
    union { float f; uint32_t i; } c;
    c.f = f;
    uint32_t x = c.i;
    uint32_t r = (x + 0x7fffu + ((x >> 16) & 1u)) >> 16;
    return (ushort)r;
}

__device__ inline float wred_sum(float v) {
#pragma unroll
    for (int m = 32; m >= 1; m >>= 1) v += __shfl_xor(v, m, 64);
    return v;
}

__device__ inline float pick4(int h, float a, float b, float c, float d) {
    float ab = (h & 1) ? b : a;
    float cd = (h & 1) ? d : c;
    return (h & 2) ? cd : ab;
}

// ---------------- weights -> W^T bf16, pre-swizzled (16B unit u ^= n&7)
__global__ __launch_bounds__(256) void prep_weights(const float* __restrict__ W_node,
                                                    const float* __restrict__ W_gat,
                                                    ushort* __restrict__ WT) {
    int b = blockIdx.x;
    const float* W = (b == 0) ? W_node : (W_gat + (size_t)(b - 1) * 16384);
    ushort* D = WT + (size_t)b * 16384;
    int t = threadIdx.x;
    int n = t >> 1;
    int k0 = (t & 1) * 64;
    for (int kk = 0; kk < 64; kk++) {
        int k = k0 + kk;
        float v = W[k * 128 + n];
        int u = (k >> 3) ^ (n & 7);
        D[n * 128 + u * 8 + (k & 7)] = f2bf(v);
    }
}

// ---------------- MFMA GEMM: out_bf[N,128] = A[N,128] @ W  (W^T staged in LDS)
// AF32 1: A is fp32, converted to bf16 in-register (node-init path).
// MODE 1: + b_node + temb epilogue. SCORES 1: emit s_src/s_dst from fp32 acc.
template <int MODE, int SCORES, int AF32>
__global__ __launch_bounds__(256) void gemm_mfma(
    const ushort* __restrict__ Abf, const float* __restrict__ Af32,
    const ushort* __restrict__ WT, ushort* __restrict__ out_bf,
    const float* __restrict__ bias, const int* __restrict__ ntypes,
    const float* __restrict__ temb,
    const float* __restrict__ asrc, const float* __restrict__ adst,
    float* __restrict__ s_src, float* __restrict__ s_dst, int nrows) {
    __shared__ ushort wlds[16384];
    int tid = threadIdx.x;
    int lane = tid & 63;
    int wid = tid >> 6;

    {
        const short8* src = (const short8*)WT;
        short8* dst = (short8*)wlds;
#pragma unroll
        for (int i = 0; i < 8; i++) dst[i * 256 + tid] = src[i * 256 + tid];
    }

    int rbase = blockIdx.x * 64 + wid * 16;
    int arow = rbase + (lane & 15);
    if (arow >= nrows) arow = nrows - 1;
    int kgrp = lane >> 4;
    short8 afr[4];
    if (AF32) {
        const float4* ap = (const float4*)(Af32 + (size_t)arow * 128);
#pragma unroll
        for (int ks = 0; ks < 4; ks++) {
            float4 f0 = ap[ks * 8 + kgrp * 2];
            float4 f1 = ap[ks * 8 + kgrp * 2 + 1];
            short8 a;
            a[0] = (short)f2bf(f0.x); a[1] = (short)f2bf(f0.y);
            a[2] = (short)f2bf(f0.z); a[3] = (short)f2bf(f0.w);
            a[4] = (short)f2bf(f1.x); a[5] = (short)f2bf(f1.y);
            a[6] = (short)f2bf(f1.z); a[7] = (short)f2bf(f1.w);
            afr[ks] = a;
        }
    } else {
        const short8* ap = (const short8*)(Abf + (size_t)arow * 128);
#pragma unroll
        for (int ks = 0; ks < 4; ks++) afr[ks] = ap[ks * 4 + kgrp];
    }

    __syncthreads();

    f32x4 acc[8];
#pragma unroll
    for (int i = 0; i < 8; i++) acc[i] = (f32x4){0.f, 0.f, 0.f, 0.f};

    int cgrp = lane & 15;
#pragma unroll
    for (int ks = 0; ks < 4; ks++) {
        short8 a = afr[ks];
#pragma unroll
        for (int nt = 0; nt < 8; nt++) {
            int n = nt * 16 + cgrp;
            int u = (ks * 4 + kgrp) ^ (n & 7);
            short8 b = *(const short8*)&wlds[n * 128 + u * 8];
            acc[nt] = __builtin_amdgcn_mfma_f32_16x16x32_bf16(a, b, acc[nt], 0, 0, 0);
        }
    }

    int nts[4];
    if (MODE == 1) {
#pragma unroll
        for (int r = 0; r < 4; r++) {
            int row = rbase + kgrp * 4 + r;
            nts[r] = (row < nrows) ? ntypes[row] : 0;
        }
    }
#pragma unroll
    for (int nt = 0; nt < 8; nt++) {
        int colc = nt * 16 + cgrp;
#pragma unroll
        for (int r = 0; r < 4; r++) {
            int row = rbase + kgrp * 4 + r;
            if (row < nrows) {
                float v = acc[nt][r];
                if (MODE == 1) v += bias[colc] + temb[nts[r] * 128 + colc];
                out_bf[(size_t)row * 128 + colc] = f2bf(v);
            }
        }
    }

    if (SCORES) {
        float as[8], ad[8];
#pragma unroll
        for (int nt = 0; nt < 8; nt++) {
            as[nt] = asrc[nt * 16 + cgrp];
            ad[nt] = adst[nt * 16 + cgrp];
        }
#pragma unroll
        for (int r = 0; r < 4; r++) {
            float ps[4], pd[4];
#pragma unroll
            for (int hh = 0; hh < 4; hh++) {
                ps[hh] = acc[2 * hh][r] * as[2 * hh] + acc[2 * hh + 1][r] * as[2 * hh + 1];
                pd[hh] = acc[2 * hh][r] * ad[2 * hh] + acc[2 * hh + 1][r] * ad[2 * hh + 1];
            }
#pragma unroll
            for (int off = 1; off < 16; off <<= 1) {
#pragma unroll
                for (int hh = 0; hh < 4; hh++) {
                    ps[hh] += __shfl_xor(ps[hh], off, 64);
                    pd[hh] += __shfl_xor(pd[hh], off, 64);
                }
            }
            int row = rbase + kgrp * 4 + r;
            if (cgrp == 0 && row < nrows) {
                ((float4*)s_src)[row] = make_float4(ps[0], ps[1], ps[2], ps[3]);
                ((float4*)s_dst)[row] = make_float4(pd[0], pd[1], pd[2], pd[3]);
            }
        }
    }
}

// ---------------- CSR build: pass A = count + slot, pass B = non-atomic fill
__global__ void count_slot(const int* __restrict__ dst, int* __restrict__ deg,
                           int* __restrict__ slot, int ne) {
    int i = blockIdx.x * blockDim.x + threadIdx.x;
    if (i < ne) slot[i] = atomicAdd(&deg[dst[i]], 1);
}

__global__ __launch_bounds__(1024) void scan_local(const int* __restrict__ cnt,
                                                   int* __restrict__ rp,
                                                   int* __restrict__ btot, int n) {
    __shared__ int lds[1024];
    int t = threadIdx.x;
    int i = blockIdx.x * 1024 + t;
    int v = (i < n) ? cnt[i] : 0;
    lds[t] = v;
    __syncthreads();
    for (int off = 1; off < 1024; off <<= 1) {
        int u = (t >= off) ? lds[t - off] : 0;
        __syncthreads();
        lds[t] += u;
        __syncthreads();
    }
    if (i < n) rp[i] = lds[t] - v;  // local exclusive
    if (t == 1023) btot[blockIdx.x] = lds[1023];
}

__global__ __launch_bounds__(64) void scan_btot(int* __restrict__ btot) {
    int t = threadIdx.x;
    int v = (t < SNB) ? btot[t] : 0;
#pragma unroll
    for (int off = 1; off < 64; off <<= 1) {
        int u = __shfl_up(v, off, 64);
        if (t >= off) v += u;
    }
    if (t < SNB) btot[t] = v;  // inclusive prefix
}

__global__ __launch_bounds__(1024) void scan_add(int* __restrict__ rp,
                                                 const int* __restrict__ btot, int n) {
    int b = blockIdx.x;
    int i = b * 1024 + threadIdx.x;
    int add = (b == 0) ? 0 : btot[b - 1];
    if (i < n) rp[i] += add;
    if (i == 0) rp[n] = EE;
}

__global__ void fill_pass(const int* __restrict__ ei, const int* __restrict__ row_ptr,
                          const int* __restrict__ slot, int* __restrict__ col, int ne) {
    int i = blockIdx.x * blockDim.x + threadIdx.x;
    if (i < ne) {
        int d = ei[ne + i];
        col[row_ptr[d] + slot[i]] = ei[i];
    }
}

// ---------------- fused GAT aggregate + bias + layernorm + residual relu
// wave per node; per 16-edge chunk: phase A (lane = edge*4+head) computes
// w = exp(lrelu(.)) once per (edge,head); phase B consumes w/col via shfl
// (shfls outside the predicated block — CDNA inactive-source returns 0).
__global__ __launch_bounds__(256) void gat_aggregate(
    const ushort* __restrict__ xh, const float* __restrict__ ssrc,
    const float* __restrict__ sdst, const int* __restrict__ row_ptr,
    const int* __restrict__ col, const float* __restrict__ bg,
    const float* __restrict__ lng, const float* __restrict__ lnb,
    ushort* __restrict__ h, int n) {
    int wid = threadIdx.x >> 6;
    int lane = threadIdx.x & 63;
    int node = blockIdx.x * 4 + wid;
    if (node >= n) return;

    int base = row_ptr[node];
    int deg = row_ptr[node + 1] - base;

    float4 sd = ((const float4*)sdst)[node];
    float4 ssf = ((const float4*)ssrc)[node];

    int aj = lane >> 2;
    int ah = lane & 3;
    float sdA = pick4(ah, sd.x, sd.y, sd.z, sd.w);

    int eg = lane >> 4;
    int g = lane & 15;
    int head = g >> 2;
    float sdH = pick4(head, sd.x, sd.y, sd.z, sd.w);
    float esH = lrelu(pick4(head, ssf.x, ssf.y, ssf.z, ssf.w) + sdH);

    float acc[8];
#pragma unroll
    for (int k = 0; k < 8; k++) acc[k] = 0.f;

    float esA = lrelu(pick4(ah, ssf.x, ssf.y, ssf.z, ssf.w) + sdA);
    float zp = (aj == 0) ? fexp(esA) : 0.f;

    if (eg == 0) {  // self-loop message once
        float w = fexp(esH);
        uint4 xv = *(const uint4*)(xh + (size_t)node * 128 + g * 8);
#pragma unroll
        for (int p = 0; p < 4; p++) {
            uint32_t u = (&xv.x)[p];
            acc[2 * p] += w * __uint_as_float(u << 16);
            acc[2 * p + 1] += w * __uint_as_float(u & 0xffff0000u);
        }
    }

    for (int c0 = 0; c0 < deg; c0 += 16) {
        int cn = deg - c0;
        if (cn > 16) cn = 16;
        int ja = aj < cn ? aj : cn - 1;
        int sA = col[base + c0 + ja];
        float sc = ssrc[sA * 4 + ah];
        float w = fexp(lrelu(sc + sdA));
        if (aj >= cn) w = 0.f;
        zp += w;
#pragma unroll
        for (int t = 0; t < 4; t++) {
            int j = t * 4 + eg;
            int s = __shfl(sA, j * 4, 64);
            float wv = __shfl(w, j * 4 + head, 64);
            if (j < cn) {
                uint4 xv = *(const uint4*)(xh + (size_t)s * 128 + g * 8);
#pragma unroll
                for (int p = 0; p < 4; p++) {
                    uint32_t u = (&xv.x)[p];
                    acc[2 * p] += wv * __uint_as_float(u << 16);
                    acc[2 * p + 1] += wv * __uint_as_float(u & 0xffff0000u);
                }
            }
        }
    }

#pragma unroll
    for (int k = 0; k < 8; k++) {
        acc[k] += __shfl_xor(acc[k], 16, 64);
        acc[k] += __shfl_xor(acc[k], 32, 64);
    }
    zp += __shfl_xor(zp, 4, 64);
    zp += __shfl_xor(zp, 8, 64);
    zp += __shfl_xor(zp, 16, 64);
    zp += __shfl_xor(zp, 32, 64);
    float z = __shfl(zp, head, 64);
    float iz = 1.f / (z + 1e-16f);

    const float4* bg4 = (const float4*)(bg + g * 8);
    float4 b0 = bg4[0], b1 = bg4[1];
    float o[8];
    o[0] = acc[0] * iz + b0.x; o[1] = acc[1] * iz + b0.y;
    o[2] = acc[2] * iz + b0.z; o[3] = acc[3] * iz + b0.w;
    o[4] = acc[4] * iz + b1.x; o[5] = acc[5] * iz + b1.y;
    o[6] = acc[6] * iz + b1.z; o[7] = acc[7] * iz + b1.w;

    float ls = 0.f;
#pragma unroll
    for (int k = 0; k < 8; k++) ls += o[k];
    float mu = wred_sum(ls) * (1.f / 512.f);
    float vs = 0.f;
#pragma unroll
    for (int k = 0; k < 8; k++) {
        o[k] -= mu;
        vs += o[k] * o[k];
    }
    float var = wred_sum(vs) * (1.f / 512.f);
    float rs = rsqrtf(var + 1e-5f);

    if (eg == 0) {
        const float4* lg4 = (const float4*)(lng + g * 8);
        const float4* lb4 = (const float4*)(lnb + g * 8);
        float4 g0 = lg4[0], g1 = lg4[1];
        float4 q0 = lb4[0], q1 = lb4[1];
        ushort* hr = h + (size_t)node * 128 + g * 8;
        short8 prev = *(const short8*)hr;
        float y[8];
        y[0] = fmaxf(o[0] * rs * g0.x + q0.x + bf2f((ushort)prev[0]), 0.f);
        y[1] = fmaxf(o[1] * rs * g0.y + q0.y + bf2f((ushort)prev[1]), 0.f);
        y[2] = fmaxf(o[2] * rs * g0.z + q0.z + bf2f((ushort)prev[2]), 0.f);
        y[3] = fmaxf(o[3] * rs * g0.w + q0.w + bf2f((ushort)prev[3]), 0.f);
        y[4] = fmaxf(o[4] * rs * g1.x + q1.x + bf2f((ushort)prev[4]), 0.f);
        y[5] = fmaxf(o[5] * rs * g1.y + q1.y + bf2f((ushort)prev[5]), 0.f);
        y[6] = fmaxf(o[6] * rs * g1.z + q1.z + bf2f((ushort)prev[6]), 0.f);
        y[7] = fmaxf(o[7] * rs * g1.w + q1.w + bf2f((ushort)prev[7]), 0.f);
        short8 ob;
#pragma unroll
        for (int k = 0; k < 8; k++) ob[k] = (short)f2bf(y[k]);
        *(short8*)hr = ob;
    }
}

// ---------------- mean pool (batch sorted -> run-length atomics), bf16 h
__global__ __launch_bounds__(256) void pool_kernel(const ushort* __restrict__ h,
                                                   const int* __restrict__ batch,
                                                   float* __restrict__ sums,
                                                   int* __restrict__ cnts, int n) {
    int c = threadIdx.x & 127;
    int half = threadIdx.x >> 7;
    int n0 = blockIdx.x * 64;
    float acc = 0.f;
    int cur = -1;
    for (int idx = half; idx < 64; idx += 2) {
        int node = n0 + idx;
        if (node >= n) break;
        int g = batch[node];
        if (g != cur) {
            if (cur >= 0) atomicAdd(&sums[cur * 128 + c], acc);
            cur = g;
            acc = 0.f;
        }
        acc += bf2f(h[(size_t)node * 128 + c]);
    }
    if (cur >= 0) atomicAdd(&sums[cur * 128 + c], acc);

    if (c == 0) {
        int cnt = 0, curg = -1;
        for (int idx = half; idx < 64; idx += 2) {
            int node = n0 + idx;
            if (node >= n) break;
            int g = batch[node];
            if (g != curg) {
                if (curg >= 0) atomicAdd(&cnts[curg], cnt);
                curg = g;
                cnt = 0;
            }
            cnt++;
        }
        if (curg >= 0) atomicAdd(&cnts[curg], cnt);
    }
}

// ---------------- MLP head: one block per graph
__global__ __launch_bounds__(256) void head_kernel(
    const float* __restrict__ sums, const int* __restrict__ cnts,
    const float* __restrict__ W1, const float* __restrict__ b1,
    const float* __restrict__ W2, const float* __restrict__ b2,
    const float* __restrict__ W3, const float* __restrict__ b3,
    float* __restrict__ out) {
    __shared__ float hg[128], z1[256], z2[128];
    int g = blockIdx.x;
    int t = threadIdx.x;
    if (t < 128) hg[t] = sums[g * 128 + t] / fmaxf((float)cnts[g], 1.f);
    __syncthreads();
    {
        float acc = b1[t];
        for (int k = 0; k < 128; k++) acc += hg[k] * W1[k * 256 + t];
        z1[t] = fmaxf(acc, 0.f);
    }
    __syncthreads();
    if (t < 128) {
        float acc = b2[t];
        for (int k = 0; k < 256; k++) acc += z1[k] * W2[k * 128 + t];
        z2[t] = fmaxf(acc, 0.f);
    }
    __syncthreads();
    if (t < NCLS) {
        float acc = b3[t];
        for (int k = 0; k < 128; k++) acc += z2[k] * W3[k * NCLS + t];
        out[g * NCLS + t] = acc;
    }
}

extern "C" void kernel_launch(void* const* d_in, const int* in_sizes, int n_in,
                              void* d_out, int out_size, void* d_ws, size_t ws_size,
                              hipStream_t stream) {
    const float* x = (const float*)d_in[0];
    const int* ei = (const int*)d_in[1];
    const int* ntypes = (const int*)d_in[2];
    const int* batch = (const int*)d_in[3];
    const float* W_node = (const float*)d_in[4];
    const float* b_node = (const float*)d_in[5];
    const float* temb = (const float*)d_in[6];
    const float* W_gat = (const float*)d_in[7];
    const float* a_src = (const float*)d_in[8];
    const float* a_dst = (const float*)d_in[9];
    const float* b_gat = (const float*)d_in[10];
    const float* ln_g = (const float*)d_in[11];
    const float* ln_b = (const float*)d_in[12];
    const float* W1 = (const float*)d_in[13];
    const float* b1 = (const float*)d_in[14];
    const float* W2 = (const float*)d_in[15];
    const float* b2 = (const float*)d_in[16];
    const float* W3 = (const float*)d_in[17];
    const float* b3 = (const float*)d_in[18];
    float* out = (float*)d_out;

    char* ws = (char*)d_ws;
    size_t off = 0;
    auto alloc = [&](size_t bytes) {
        void* p = ws + off;
        off += (bytes + 255) & ~(size_t)255;
        return p;
    };
    ushort* hb = (ushort*)alloc((size_t)NN * 128 * 2);   // bf16 h
    ushort* xhb = (ushort*)alloc((size_t)NN * 128 * 2);  // bf16 xh (layer GEMM out)
    ushort* WT = (ushort*)alloc((size_t)4 * 16384 * 2);
    float* ssrc = (float*)alloc((size_t)NN * 4 * 4);
    float* sdst = (float*)alloc((size_t)NN * 4 * 4);
    int* rowp = (int*)alloc((size_t)(NN + 1) * 4);
    int* fillc = (int*)alloc((size_t)NN * 4);
    int* col = (int*)alloc((size_t)EE * 4);
    int* slot = (int*)alloc((size_t)EE * 4);
    float* psum = (float*)alloc((size_t)NGRAPH * 128 * 4);
    int* pcnt = (int*)alloc((size_t)NGRAPH * 4);
    int* btot = (int*)alloc((size_t)SNB * 4);

    hipError_t e0;
    e0 = hipMemsetAsync(fillc, 0, (size_t)NN * 4, stream); (void)e0;
    e0 = hipMemsetAsync(psum, 0, (size_t)NGRAPH * 128 * 4, stream); (void)e0;
    e0 = hipMemsetAsync(pcnt, 0, (size_t)NGRAPH * 4, stream); (void)e0;

    // prep: weights -> W^T bf16 swizzled
    prep_weights<<<4, 256, 0, stream>>>(W_node, W_gat, WT);

    // CSR build: count+slot -> scan -> non-atomic fill
    count_slot<<<(EE + 255) / 256, 256, 0, stream>>>(ei + EE, fillc, slot, EE);
    scan_local<<<SNB, 1024, 0, stream>>>(fillc, rowp, btot, NN);
    scan_btot<<<1, 64, 0, stream>>>(btot);
    scan_add<<<SNB, 1024, 0, stream>>>(rowp, btot, NN);
    fill_pass<<<(EE + 255) / 256, 256, 0, stream>>>(ei, rowp, slot, col, EE);

    // node init: h = x@W_node + b_node + temb[ntypes]  (fp32 A read, bf16 out)
    int gemm_grid = (NN + 63) / 64;
    gemm_mfma<1, 0, 1><<<gemm_grid, 256, 0, stream>>>(
        nullptr, x, WT, hb, b_node, ntypes, temb, nullptr, nullptr, nullptr, nullptr, NN);

    for (int l = 0; l < LL; l++) {
        gemm_mfma<0, 1, 0><<<gemm_grid, 256, 0, stream>>>(
            hb, nullptr, WT + (size_t)(l + 1) * 16384, xhb, nullptr, nullptr, nullptr,
            a_src + l * HEADS * CC, a_dst + l * HEADS * CC, ssrc, sdst, NN);
        gat_aggregate<<<(NN + 3) / 4, 256, 0, stream>>>(
            xhb, ssrc, sdst, rowp, col, b_gat + l * 128, ln_g + l * 128, ln_b + l * 128,
            hb, NN);
    }

    pool_kernel<<<(NN + 63) / 64, 256, 0, stream>>>(hb, batch, psum, pcnt, NN);
    head_kernel<<<NGRAPH, 256, 0, stream>>>(psum, pcnt, W1, b1, W2, b2, W3, b3, out);
}